// Round 1
// baseline (1646.673 us; speedup 1.0000x reference)
//
#include <hip/hip_runtime.h>
#include <math.h>

#define DEV __device__ __forceinline__

DEV float sigm(float x) { return 1.0f / (1.0f + __expf(-x)); }

// ============================ utility kernels ============================

__global__ void fill_i32_kernel(int* p, int v, int n) {
  int i = blockIdx.x * blockDim.x + threadIdx.x;
  if (i < n) p[i] = v;
}

// count incoming edges per dst (including self loops)
__global__ void count_edges_kernel(const int* __restrict__ ei, int* __restrict__ cnt,
                                   int E, int N) {
  int e = blockIdx.x * blockDim.x + threadIdx.x;
  if (e >= E + N) return;
  int d = (e < E) ? ei[E + e] : (e - E);
  atomicAdd(&cnt[d], 1);
}

// in-place exclusive scan within each 256-block; blockSums gets block totals
__global__ void scan1_kernel(int* data, int* blockSums) {
  __shared__ int sh[256];
  int tid = threadIdx.x;
  int gid = blockIdx.x * 256 + tid;
  int v = data[gid];
  sh[tid] = v;
  __syncthreads();
  int val = v;
  for (int off = 1; off < 256; off <<= 1) {
    int add = (tid >= off) ? sh[tid - off] : 0;
    __syncthreads();
    val += add;
    sh[tid] = val;
    __syncthreads();
  }
  data[gid] = val - v;  // exclusive
  if (tid == 255) blockSums[blockIdx.x] = val;
}

// single block: exclusive scan of the 256 block sums, in place
__global__ void scan2_kernel(int* blockSums) {
  __shared__ int sh[256];
  int tid = threadIdx.x;
  int v = blockSums[tid];
  sh[tid] = v;
  __syncthreads();
  int val = v;
  for (int off = 1; off < 256; off <<= 1) {
    int add = (tid >= off) ? sh[tid - off] : 0;
    __syncthreads();
    val += add;
    sh[tid] = val;
    __syncthreads();
  }
  blockSums[tid] = val - v;
}

__global__ void scan3_kernel(int* row_start, int* cursor, const int* blockOff,
                             int N, int Et) {
  int tid = threadIdx.x;
  int gid = blockIdx.x * 256 + tid;
  int v = row_start[gid] + blockOff[blockIdx.x];
  row_start[gid] = v;
  cursor[gid] = v;
  if (gid == 0) row_start[N] = Et;
}

__global__ void scatter_kernel(const int* __restrict__ ei, int* __restrict__ cursor,
                               int* __restrict__ srcs, int E, int N) {
  int e = blockIdx.x * blockDim.x + threadIdx.x;
  if (e >= E + N) return;
  int s, d;
  if (e < E) { s = ei[e]; d = ei[E + e]; } else { s = e - E; d = e - E; }
  int pos = atomicAdd(&cursor[d], 1);
  srcs[pos] = s;
}

// ============================ GEMM ============================
// C[N x M] = act(A[N x K] @ W[K x M] + bias). Row-major, N%64==0, M%64==0.
// 64x64 tile per block, 256 threads, 4x4 microtile, BK=16.
__global__ __launch_bounds__(256) void gemm_f32(
    const float* __restrict__ A, int lda,
    const float* __restrict__ W, int ldw,
    const float* __restrict__ bias,
    float* __restrict__ C, int ldc,
    int K, int act) {
  __shared__ float As[16][65];
  __shared__ float Ws[16][64];
  const int tid = threadIdx.x;
  const long long r0 = (long long)blockIdx.y * 64;
  const int c0 = blockIdx.x * 64;
  const int tx = tid & 15, ty = tid >> 4;

  float acc[4][4] = {};

  for (int k0 = 0; k0 < K; k0 += 16) {
    // A tile: 64 rows x 16 k
    {
      int row = tid & 63;
      int kb = (tid >> 6) * 4;
      const float* ap = A + (r0 + row) * lda + k0 + kb;
#pragma unroll
      for (int j = 0; j < 4; ++j) {
        int kk = kb + j;
        As[kk][row] = (k0 + kk < K) ? ap[j] : 0.0f;
      }
    }
    // W tile: 16 k x 64 cols
    {
      int kk = tid >> 4;
      int cb = (tid & 15) * 4;
      const float* wp = W + (long long)(k0 + kk) * ldw + c0 + cb;
      bool ok = (k0 + kk) < K;
#pragma unroll
      for (int j = 0; j < 4; ++j)
        Ws[kk][cb + j] = ok ? wp[j] : 0.0f;
    }
    __syncthreads();
#pragma unroll
    for (int kk = 0; kk < 16; ++kk) {
      float a0 = As[kk][ty * 4 + 0], a1 = As[kk][ty * 4 + 1];
      float a2 = As[kk][ty * 4 + 2], a3 = As[kk][ty * 4 + 3];
      float b0 = Ws[kk][tx * 4 + 0], b1 = Ws[kk][tx * 4 + 1];
      float b2 = Ws[kk][tx * 4 + 2], b3 = Ws[kk][tx * 4 + 3];
      acc[0][0] += a0 * b0; acc[0][1] += a0 * b1; acc[0][2] += a0 * b2; acc[0][3] += a0 * b3;
      acc[1][0] += a1 * b0; acc[1][1] += a1 * b1; acc[1][2] += a1 * b2; acc[1][3] += a1 * b3;
      acc[2][0] += a2 * b0; acc[2][1] += a2 * b1; acc[2][2] += a2 * b2; acc[2][3] += a2 * b3;
      acc[3][0] += a3 * b0; acc[3][1] += a3 * b1; acc[3][2] += a3 * b2; acc[3][3] += a3 * b3;
    }
    __syncthreads();
  }

#pragma unroll
  for (int i = 0; i < 4; ++i) {
    long long r = r0 + ty * 4 + i;
#pragma unroll
    for (int j = 0; j < 4; ++j) {
      int c = c0 + tx * 4 + j;
      float v = acc[i][j] + (bias ? bias[c] : 0.0f);
      if (act == 1) v = fmaxf(v, 0.0f);
      C[r * ldc + c] = v;
    }
  }
}

// ============================ GAT helpers ============================

// s[i] = dot(G[i,:], a_src), t[i] = dot(G[i,:], a_dst); one wave per node
__global__ __launch_bounds__(256) void st_kernel(
    const float* __restrict__ G, const float* __restrict__ asrc,
    const float* __restrict__ adst, float* __restrict__ s, float* __restrict__ t,
    int N, int fo) {
  int w = (blockIdx.x * blockDim.x + threadIdx.x) >> 6;
  int lane = threadIdx.x & 63;
  if (w >= N) return;
  const float* row = G + (long long)w * fo;
  float ps = 0.0f, pt = 0.0f;
  for (int c = lane; c < fo; c += 64) {
    float v = row[c];
    ps += v * asrc[c];
    pt += v * adst[c];
  }
  for (int off = 32; off; off >>= 1) {
    ps += __shfl_xor(ps, off, 64);
    pt += __shfl_xor(pt, off, 64);
  }
  if (lane == 0) { s[w] = ps; t[w] = pt; }
}

// one wave per dst node: softmax over incoming edges + weighted aggregation
template <int FO>
__global__ __launch_bounds__(256) void gat_aggregate(
    const float* __restrict__ G, const float* __restrict__ s,
    const float* __restrict__ t, const int* __restrict__ row_start,
    const int* __restrict__ srcs, const float* __restrict__ bias,
    float* __restrict__ out, int ldc, int N) {
  int d = (blockIdx.x * blockDim.x + threadIdx.x) >> 6;
  int lane = threadIdx.x & 63;
  if (d >= N) return;
  int start = row_start[d], end = row_start[d + 1];
  float td = t[d];

  // pass 1: max
  float m = -INFINITY;
  for (int j = start + lane; j < end; j += 64) {
    float e = s[srcs[j]] + td;
    e = (e >= 0.0f) ? e : 0.2f * e;
    m = fmaxf(m, e);
  }
  for (int off = 32; off; off >>= 1) m = fmaxf(m, __shfl_xor(m, off, 64));

  // pass 2: denom
  float dsum = 0.0f;
  for (int j = start + lane; j < end; j += 64) {
    float e = s[srcs[j]] + td;
    e = (e >= 0.0f) ? e : 0.2f * e;
    dsum += __expf(e - m);
  }
  for (int off = 32; off; off >>= 1) dsum += __shfl_xor(dsum, off, 64);
  float inv = 1.0f / dsum;

  // pass 3: weighted accumulation (lanes = feature cols, coalesced gathers)
  float acc0 = 0.0f, acc1 = 0.0f;
  for (int j = start; j < end; ++j) {
    int srcj = srcs[j];
    float e = s[srcj] + td;
    e = (e >= 0.0f) ? e : 0.2f * e;
    float alpha = __expf(e - m) * inv;
    acc0 += alpha * G[(long long)srcj * FO + lane];
    if (FO == 128) acc1 += alpha * G[(long long)srcj * FO + 64 + lane];
  }
  float o0 = fmaxf(acc0 + bias[lane], 0.0f);
  out[(long long)d * ldc + lane] = o0;
  if (FO == 128) {
    float o1 = fmaxf(acc1 + bias[64 + lane], 0.0f);
    out[(long long)d * ldc + 64 + lane] = o1;
  }
}

// ============================ LSTM / head ============================

// gates[N x 256] -> h[N x 64]; c = sig(i)*tanh(g); h = sig(o)*tanh(c)
__global__ void lstm_act_kernel(const float* __restrict__ gates,
                                float* __restrict__ h, int N) {
  int idx = blockIdx.x * blockDim.x + threadIdx.x;
  if (idx >= N * 64) return;
  int i = idx >> 6, c = idx & 63;
  const float* g = gates + (long long)i * 256;
  float gi = g[c], gg = g[128 + c], go = g[192 + c];
  float cc = sigm(gi) * tanhf(gg);
  h[idx] = sigm(go) * tanhf(cc);
}

// out[i] = dot(Z[i,:64], w) + b
__global__ void lin3_kernel(const float* __restrict__ Z, const float* __restrict__ w,
                            const float* __restrict__ b, float* __restrict__ out, int N) {
  int i = blockIdx.x * blockDim.x + threadIdx.x;
  if (i >= N) return;
  const float4* z4 = (const float4*)(Z + (long long)i * 64);
  const float4* w4 = (const float4*)w;
  float acc = 0.0f;
#pragma unroll
  for (int k = 0; k < 16; ++k) {
    float4 a = z4[k], ww = w4[k];
    acc += a.x * ww.x + a.y * ww.y + a.z * ww.z + a.w * ww.w;
  }
  out[i] = acc + b[0];
}

// ============================ launcher ============================

static inline void launch_gemm(const float* A, int lda, const float* W, int ldw,
                               const float* bias, float* C, int ldc,
                               int N, int K, int M, int act, hipStream_t stream) {
  dim3 grid(M / 64, N / 64);
  hipLaunchKernelGGL(gemm_f32, grid, dim3(256), 0, stream,
                     A, lda, W, ldw, bias, C, ldc, K, act);
}

extern "C" void kernel_launch(void* const* d_in, const int* in_sizes, int n_in,
                              void* d_out, int out_size, void* d_ws, size_t ws_size,
                              hipStream_t stream) {
  const int N = 65536, E = 1048576;
  const int Et = E + N;

  const float* x        = (const float*)d_in[0];   // N x 445
  const int*   ei       = (const int*)d_in[1];     // 2 x E
  const float* poi1_W   = (const float*)d_in[2];
  const float* poi1_b   = (const float*)d_in[3];
  const float* poi2_W   = (const float*)d_in[4];
  const float* poi2_b   = (const float*)d_in[5];
  const float* svi1_W   = (const float*)d_in[6];
  const float* svi1_b   = (const float*)d_in[7];
  const float* svi2_W   = (const float*)d_in[8];
  const float* svi2_b   = (const float*)d_in[9];
  const float* all1_W   = (const float*)d_in[10];
  const float* all1_b   = (const float*)d_in[11];
  const float* all2_W   = (const float*)d_in[12];
  const float* all2_b   = (const float*)d_in[13];
  const float* gat1_W   = (const float*)d_in[14];
  const float* gat1_b   = (const float*)d_in[15];
  const float* gat1_as  = (const float*)d_in[16];
  const float* gat1_ad  = (const float*)d_in[17];
  const float* gat2_W   = (const float*)d_in[18];
  const float* gat2_b   = (const float*)d_in[19];
  const float* gat2_as  = (const float*)d_in[20];
  const float* gat2_ad  = (const float*)d_in[21];
  const float* gat3_W   = (const float*)d_in[22];
  const float* gat3_b   = (const float*)d_in[23];
  const float* gat3_as  = (const float*)d_in[24];
  const float* gat3_ad  = (const float*)d_in[25];
  const float* lstm_Wih0= (const float*)d_in[26];  // 24 x 256
  const float* lstm_Wih = (const float*)d_in[27];  // 23 x 64 x 256
  // d_in[28] = lstm_Whh : UNUSED by the reference
  const float* lstm_b   = (const float*)d_in[29];  // 24 x 256
  const float* time1_W  = (const float*)d_in[30];
  const float* time1_b  = (const float*)d_in[31];
  const float* time2_W  = (const float*)d_in[32];
  const float* time2_b  = (const float*)d_in[33];
  const float* lin1_W   = (const float*)d_in[34];
  const float* lin1_b   = (const float*)d_in[35];
  const float* lin2_W   = (const float*)d_in[36];
  const float* lin2_b   = (const float*)d_in[37];
  const float* lin3_W   = (const float*)d_in[38];
  const float* lin3_b   = (const float*)d_in[39];
  float* out = (float*)d_out;

  // ---- workspace layout (floats then ints), ~190 MB total ----
  float* wsf   = (float*)d_ws;
  float* R192  = wsf;                         // N x 192  (concat poi|svi)
  float* RA    = R192 + (size_t)N * 192;      // N x 128  (general)
  float* RA2   = RA + (size_t)N * 64;         // second N x 64 half of RA
  float* RB    = RA + (size_t)N * 128;        // N x 256  (gates / general)
  float* Rz    = RB + (size_t)N * 256;        // N x 128  (concat gat3|time)
  float* sArr  = Rz + (size_t)N * 128;        // N
  float* tArr  = sArr + N;                    // N
  int* ints      = (int*)(tArr + N);
  int* row_start = ints;                      // N+1  (also used as cnt)
  int* cursor    = row_start + (N + 1);       // N
  int* srcs      = cursor + N;                // Et
  int* blockSums = srcs + Et;                 // 256

  const int TB = 256;
  const int edgeBlocks = (Et + TB - 1) / TB;

  // ---- build CSR (dst-sorted src list); shared by all 3 GAT layers ----
  hipLaunchKernelGGL(fill_i32_kernel, dim3((N + TB - 1) / TB), dim3(TB), 0, stream,
                     row_start, 0, N);
  hipLaunchKernelGGL(count_edges_kernel, dim3(edgeBlocks), dim3(TB), 0, stream,
                     ei, row_start, E, N);
  hipLaunchKernelGGL(scan1_kernel, dim3(N / 256), dim3(256), 0, stream,
                     row_start, blockSums);
  hipLaunchKernelGGL(scan2_kernel, dim3(1), dim3(256), 0, stream, blockSums);
  hipLaunchKernelGGL(scan3_kernel, dim3(N / 256), dim3(256), 0, stream,
                     row_start, cursor, blockSums, N, Et);
  hipLaunchKernelGGL(scatter_kernel, dim3(edgeBlocks), dim3(TB), 0, stream,
                     ei, cursor, srcs, E, N);

  // ---- MLP towers ----
  // poi: x[:,3:16] -> 64 -> 64 (into R192 cols 0..63)
  launch_gemm(x + 3, 445, poi1_W, 64, poi1_b, RA, 64, N, 13, 64, 1, stream);
  launch_gemm(RA, 64, poi2_W, 64, poi2_b, R192, 192, N, 64, 64, 1, stream);
  // svi: x[:,56:421] -> 128 -> 128 (into R192 cols 64..191)
  launch_gemm(x + 56, 445, svi1_W, 128, svi1_b, RB, 128, N, 365, 128, 1, stream);
  launch_gemm(RB, 128, svi2_W, 128, svi2_b, R192 + 64, 192, N, 128, 128, 1, stream);
  // all: 192 -> 128 -> 128  => H in RB
  launch_gemm(R192, 192, all1_W, 128, all1_b, RA, 128, N, 192, 128, 1, stream);
  launch_gemm(RA, 128, all2_W, 128, all2_b, RB, 128, N, 128, 128, 1, stream);

  const int waveBlocks = N / 4;  // 4 waves (dst nodes) per 256-thread block

  // ---- GAT1: RB(H) -> RA(G) -> aggregate -> RB(H2) ----
  launch_gemm(RB, 128, gat1_W, 128, nullptr, RA, 128, N, 128, 128, 0, stream);
  hipLaunchKernelGGL(st_kernel, dim3(waveBlocks), dim3(256), 0, stream,
                     RA, gat1_as, gat1_ad, sArr, tArr, N, 128);
  hipLaunchKernelGGL((gat_aggregate<128>), dim3(waveBlocks), dim3(256), 0, stream,
                     RA, sArr, tArr, row_start, srcs, gat1_b, RB, 128, N);
  // ---- GAT2 ----
  launch_gemm(RB, 128, gat2_W, 128, nullptr, RA, 128, N, 128, 128, 0, stream);
  hipLaunchKernelGGL(st_kernel, dim3(waveBlocks), dim3(256), 0, stream,
                     RA, gat2_as, gat2_ad, sArr, tArr, N, 128);
  hipLaunchKernelGGL((gat_aggregate<128>), dim3(waveBlocks), dim3(256), 0, stream,
                     RA, sArr, tArr, row_start, srcs, gat2_b, RB, 128, N);
  // ---- GAT3 (fo=64, output into Rz cols 0..63) ----
  launch_gemm(RB, 128, gat3_W, 64, nullptr, RA, 64, N, 128, 64, 0, stream);
  hipLaunchKernelGGL(st_kernel, dim3(waveBlocks), dim3(256), 0, stream,
                     RA, gat3_as, gat3_ad, sArr, tArr, N, 64);
  hipLaunchKernelGGL((gat_aggregate<64>), dim3(waveBlocks), dim3(256), 0, stream,
                     RA, sArr, tArr, row_start, srcs, gat3_b, Rz, 128, N);

  // ---- "LSTM": only layers 0..2 matter (t = hs[2]); Whh/f-gate/cell unused ----
  const int actBlocks = (N * 64 + TB - 1) / TB;
  launch_gemm(x + 421, 445, lstm_Wih0, 256, lstm_b, RB, 256, N, 24, 256, 0, stream);
  hipLaunchKernelGGL(lstm_act_kernel, dim3(actBlocks), dim3(TB), 0, stream, RB, RA, N);
  launch_gemm(RA, 64, lstm_Wih, 256, lstm_b + 256, RB, 256, N, 64, 256, 0, stream);
  hipLaunchKernelGGL(lstm_act_kernel, dim3(actBlocks), dim3(TB), 0, stream, RB, RA2, N);
  launch_gemm(RA2, 64, lstm_Wih + 64 * 256, 256, lstm_b + 512, RB, 256, N, 64, 256, 0, stream);
  hipLaunchKernelGGL(lstm_act_kernel, dim3(actBlocks), dim3(TB), 0, stream, RB, RA, N);

  // ---- time MLP: h2 -> 64 -> 64 (into Rz cols 64..127) ----
  launch_gemm(RA, 64, time1_W, 64, time1_b, RA2, 64, N, 64, 64, 1, stream);
  launch_gemm(RA2, 64, time2_W, 64, time2_b, Rz + 64, 128, N, 64, 64, 1, stream);

  // ---- head: z = [gat3|time] (N x 128) -> 64 -> 64 -> 1 ----
  launch_gemm(Rz, 128, lin1_W, 64, lin1_b, RA, 64, N, 128, 64, 1, stream);
  launch_gemm(RA, 64, lin2_W, 64, lin2_b, RA2, 64, N, 64, 64, 1, stream);
  hipLaunchKernelGGL(lin3_kernel, dim3((N + TB - 1) / TB), dim3(TB), 0, stream,
                     RA2, lin3_W, lin3_b, out, N);
}

// Round 2
// 1589.438 us; speedup vs baseline: 1.0360x; 1.0360x over previous
//
#include <hip/hip_runtime.h>
#include <math.h>

#define DEV __device__ __forceinline__

DEV float sigm(float x) { return 1.0f / (1.0f + __expf(-x)); }

// ============================ utility kernels ============================

__global__ void fill_i32_kernel(int* p, int v, int n) {
  int i = blockIdx.x * blockDim.x + threadIdx.x;
  if (i < n) p[i] = v;
}

// count incoming edges per dst (including self loops)
__global__ void count_edges_kernel(const int* __restrict__ ei, int* __restrict__ cnt,
                                   int E, int N) {
  int e = blockIdx.x * blockDim.x + threadIdx.x;
  if (e >= E + N) return;
  int d = (e < E) ? ei[E + e] : (e - E);
  atomicAdd(&cnt[d], 1);
}

// in-place exclusive scan within each 256-block; blockSums gets block totals
__global__ void scan1_kernel(int* data, int* blockSums) {
  __shared__ int sh[256];
  int tid = threadIdx.x;
  int gid = blockIdx.x * 256 + tid;
  int v = data[gid];
  sh[tid] = v;
  __syncthreads();
  int val = v;
  for (int off = 1; off < 256; off <<= 1) {
    int add = (tid >= off) ? sh[tid - off] : 0;
    __syncthreads();
    val += add;
    sh[tid] = val;
    __syncthreads();
  }
  data[gid] = val - v;  // exclusive
  if (tid == 255) blockSums[blockIdx.x] = val;
}

// single block: exclusive scan of the 256 block sums, in place
__global__ void scan2_kernel(int* blockSums) {
  __shared__ int sh[256];
  int tid = threadIdx.x;
  int v = blockSums[tid];
  sh[tid] = v;
  __syncthreads();
  int val = v;
  for (int off = 1; off < 256; off <<= 1) {
    int add = (tid >= off) ? sh[tid - off] : 0;
    __syncthreads();
    val += add;
    sh[tid] = val;
    __syncthreads();
  }
  blockSums[tid] = val - v;
}

__global__ void scan3_kernel(int* row_start, int* cursor, const int* blockOff,
                             int N, int Et) {
  int tid = threadIdx.x;
  int gid = blockIdx.x * 256 + tid;
  int v = row_start[gid] + blockOff[blockIdx.x];
  row_start[gid] = v;
  cursor[gid] = v;
  if (gid == 0) row_start[N] = Et;
}

__global__ void scatter_kernel(const int* __restrict__ ei, int* __restrict__ cursor,
                               int* __restrict__ srcs, int E, int N) {
  int e = blockIdx.x * blockDim.x + threadIdx.x;
  if (e >= E + N) return;
  int s, d;
  if (e < E) { s = ei[e]; d = ei[E + e]; } else { s = e - E; d = e - E; }
  int pos = atomicAdd(&cursor[d], 1);
  srcs[pos] = s;
}

// ============================ GEMM ============================
// C[N x M] = act(A[N x K] @ W[K x M] + bias). Row-major.
// Block tile BM x BN, microtile TM x TN (TN==8, split into two float4 col
// groups at tx*4 and BN/2+tx*4 to keep LDS column reads 2-way-aliased max).
template <int BM, int BN, int TM, int TN>
__global__ __launch_bounds__((BM / TM) * (BN / TN)) void gemm_f32_tile(
    const float* __restrict__ A, int lda,
    const float* __restrict__ W, int ldw,
    const float* __restrict__ bias,
    float* __restrict__ C, int ldc,
    int K, int act) {
  constexpr int BK = 16;
  constexpr int THREADS = (BM / TM) * (BN / TN);
  constexpr int NX = BN / TN;
  __shared__ float As[BK][BM + 4];
  __shared__ float Ws[BK][BN];
  const int tid = threadIdx.x;
  const int tx = tid % NX;
  const int ty = tid / NX;
  const long long r0 = (long long)blockIdx.y * BM;
  const int c0 = blockIdx.x * BN;

  float acc[TM][TN] = {};

  for (int k0 = 0; k0 < K; k0 += BK) {
    // stage A: BM rows x BK k, transposed into As[kk][row]
    for (int s = tid; s < BM * 2; s += THREADS) {
      int row = s >> 1;
      int kb = (s & 1) * 8;
      const float* ap = A + (r0 + row) * lda + k0 + kb;
#pragma unroll
      for (int j = 0; j < 8; ++j) {
        int kk = kb + j;
        As[kk][row] = (k0 + kk < K) ? ap[j] : 0.0f;
      }
    }
    // stage W: BK x BN
    for (int s = tid; s < BN * 2; s += THREADS) {
      int kk = s / (BN / 8);
      int cb = (s % (BN / 8)) * 8;
      bool ok = (k0 + kk) < K;
      const float* wp = W + (long long)(k0 + kk) * ldw + c0 + cb;
#pragma unroll
      for (int j = 0; j < 8; ++j)
        Ws[kk][cb + j] = ok ? wp[j] : 0.0f;
    }
    __syncthreads();
#pragma unroll
    for (int kk = 0; kk < BK; ++kk) {
      float a_reg[TM], b_reg[TN];
#pragma unroll
      for (int i = 0; i < TM; ++i) a_reg[i] = As[kk][ty * TM + i];
#pragma unroll
      for (int j = 0; j < 4; ++j) {
        b_reg[j] = Ws[kk][tx * 4 + j];
        b_reg[4 + j] = Ws[kk][BN / 2 + tx * 4 + j];
      }
#pragma unroll
      for (int i = 0; i < TM; ++i)
#pragma unroll
        for (int j = 0; j < TN; ++j)
          acc[i][j] += a_reg[i] * b_reg[j];
    }
    __syncthreads();
  }

#pragma unroll
  for (int i = 0; i < TM; ++i) {
    long long r = r0 + ty * TM + i;
    float* cpA = C + r * ldc + c0 + tx * 4;
    float* cpB = C + r * ldc + c0 + BN / 2 + tx * 4;
#pragma unroll
    for (int j = 0; j < 4; ++j) {
      float vA = acc[i][j] + (bias ? bias[c0 + tx * 4 + j] : 0.0f);
      float vB = acc[i][4 + j] + (bias ? bias[c0 + BN / 2 + tx * 4 + j] : 0.0f);
      if (act == 1) { vA = fmaxf(vA, 0.0f); vB = fmaxf(vB, 0.0f); }
      cpA[j] = vA;
      cpB[j] = vB;
    }
  }
}

// ============================ GAT helpers ============================

// s[i] = dot(G[i,:], a_src), t[i] = dot(G[i,:], a_dst); one wave per node
__global__ __launch_bounds__(256) void st_kernel(
    const float* __restrict__ G, const float* __restrict__ asrc,
    const float* __restrict__ adst, float* __restrict__ s, float* __restrict__ t,
    int N, int fo) {
  int w = (blockIdx.x * blockDim.x + threadIdx.x) >> 6;
  int lane = threadIdx.x & 63;
  if (w >= N) return;
  const float* row = G + (long long)w * fo;
  float ps = 0.0f, pt = 0.0f;
  for (int c = lane; c < fo; c += 64) {
    float v = row[c];
    ps += v * asrc[c];
    pt += v * adst[c];
  }
  for (int off = 32; off; off >>= 1) {
    ps += __shfl_xor(ps, off, 64);
    pt += __shfl_xor(pt, off, 64);
  }
  if (lane == 0) { s[w] = ps; t[w] = pt; }
}

// one wave per dst node: softmax over incoming edges + weighted aggregation
template <int FO>
__global__ __launch_bounds__(256) void gat_aggregate(
    const float* __restrict__ G, const float* __restrict__ s,
    const float* __restrict__ t, const int* __restrict__ row_start,
    const int* __restrict__ srcs, const float* __restrict__ bias,
    float* __restrict__ out, int ldc, int N) {
  int d = (blockIdx.x * blockDim.x + threadIdx.x) >> 6;
  int lane = threadIdx.x & 63;
  if (d >= N) return;
  int start = row_start[d], end = row_start[d + 1];
  float td = t[d];

  // pass 1: max
  float m = -INFINITY;
  for (int j = start + lane; j < end; j += 64) {
    float e = s[srcs[j]] + td;
    e = (e >= 0.0f) ? e : 0.2f * e;
    m = fmaxf(m, e);
  }
  for (int off = 32; off; off >>= 1) m = fmaxf(m, __shfl_xor(m, off, 64));

  // pass 2: denom
  float dsum = 0.0f;
  for (int j = start + lane; j < end; j += 64) {
    float e = s[srcs[j]] + td;
    e = (e >= 0.0f) ? e : 0.2f * e;
    dsum += __expf(e - m);
  }
  for (int off = 32; off; off >>= 1) dsum += __shfl_xor(dsum, off, 64);
  float inv = 1.0f / dsum;

  // pass 3: weighted accumulation (lanes = feature cols, coalesced gathers)
  float acc0 = 0.0f, acc1 = 0.0f;
  for (int j = start; j < end; ++j) {
    int srcj = srcs[j];
    float e = s[srcj] + td;
    e = (e >= 0.0f) ? e : 0.2f * e;
    float alpha = __expf(e - m) * inv;
    acc0 += alpha * G[(long long)srcj * FO + lane];
    if (FO == 128) acc1 += alpha * G[(long long)srcj * FO + 64 + lane];
  }
  float o0 = fmaxf(acc0 + bias[lane], 0.0f);
  out[(long long)d * ldc + lane] = o0;
  if (FO == 128) {
    float o1 = fmaxf(acc1 + bias[64 + lane], 0.0f);
    out[(long long)d * ldc + 64 + lane] = o1;
  }
}

// ============================ LSTM / head ============================

// gates[N x 256] -> h[N x 64]; c = sig(i)*tanh(g); h = sig(o)*tanh(c)
__global__ void lstm_act_kernel(const float* __restrict__ gates,
                                float* __restrict__ h, int N) {
  int idx = blockIdx.x * blockDim.x + threadIdx.x;
  if (idx >= N * 64) return;
  int i = idx >> 6, c = idx & 63;
  const float* g = gates + (long long)i * 256;
  float gi = g[c], gg = g[128 + c], go = g[192 + c];
  float cc = sigm(gi) * tanhf(gg);
  h[idx] = sigm(go) * tanhf(cc);
}

// out[i] = dot(Z[i,:64], w) + b
__global__ void lin3_kernel(const float* __restrict__ Z, const float* __restrict__ w,
                            const float* __restrict__ b, float* __restrict__ out, int N) {
  int i = blockIdx.x * blockDim.x + threadIdx.x;
  if (i >= N) return;
  const float4* z4 = (const float4*)(Z + (long long)i * 64);
  const float4* w4 = (const float4*)w;
  float acc = 0.0f;
#pragma unroll
  for (int k = 0; k < 16; ++k) {
    float4 a = z4[k], ww = w4[k];
    acc += a.x * ww.x + a.y * ww.y + a.z * ww.z + a.w * ww.w;
  }
  out[i] = acc + b[0];
}

// ============================ launcher ============================

static inline void launch_gemm(const float* A, int lda, const float* W, int ldw,
                               const float* bias, float* C, int ldc,
                               int N, int K, int M, int act, hipStream_t stream) {
  if (M % 128 == 0) {
    dim3 grid(M / 128, N / 128);
    hipLaunchKernelGGL((gemm_f32_tile<128, 128, 8, 8>), grid, dim3(256), 0, stream,
                       A, lda, W, ldw, bias, C, ldc, K, act);
  } else {
    dim3 grid(M / 64, N / 128);
    hipLaunchKernelGGL((gemm_f32_tile<128, 64, 4, 8>), grid, dim3(256), 0, stream,
                       A, lda, W, ldw, bias, C, ldc, K, act);
  }
}

extern "C" void kernel_launch(void* const* d_in, const int* in_sizes, int n_in,
                              void* d_out, int out_size, void* d_ws, size_t ws_size,
                              hipStream_t stream) {
  const int N = 65536, E = 1048576;
  const int Et = E + N;

  const float* x        = (const float*)d_in[0];   // N x 445
  const int*   ei       = (const int*)d_in[1];     // 2 x E
  const float* poi1_W   = (const float*)d_in[2];
  const float* poi1_b   = (const float*)d_in[3];
  const float* poi2_W   = (const float*)d_in[4];
  const float* poi2_b   = (const float*)d_in[5];
  const float* svi1_W   = (const float*)d_in[6];
  const float* svi1_b   = (const float*)d_in[7];
  const float* svi2_W   = (const float*)d_in[8];
  const float* svi2_b   = (const float*)d_in[9];
  const float* all1_W   = (const float*)d_in[10];
  const float* all1_b   = (const float*)d_in[11];
  const float* all2_W   = (const float*)d_in[12];
  const float* all2_b   = (const float*)d_in[13];
  const float* gat1_W   = (const float*)d_in[14];
  const float* gat1_b   = (const float*)d_in[15];
  const float* gat1_as  = (const float*)d_in[16];
  const float* gat1_ad  = (const float*)d_in[17];
  const float* gat2_W   = (const float*)d_in[18];
  const float* gat2_b   = (const float*)d_in[19];
  const float* gat2_as  = (const float*)d_in[20];
  const float* gat2_ad  = (const float*)d_in[21];
  const float* gat3_W   = (const float*)d_in[22];
  const float* gat3_b   = (const float*)d_in[23];
  const float* gat3_as  = (const float*)d_in[24];
  const float* gat3_ad  = (const float*)d_in[25];
  const float* lstm_Wih0= (const float*)d_in[26];  // 24 x 256
  const float* lstm_Wih = (const float*)d_in[27];  // 23 x 64 x 256
  // d_in[28] = lstm_Whh : UNUSED by the reference
  const float* lstm_b   = (const float*)d_in[29];  // 24 x 256
  const float* time1_W  = (const float*)d_in[30];
  const float* time1_b  = (const float*)d_in[31];
  const float* time2_W  = (const float*)d_in[32];
  const float* time2_b  = (const float*)d_in[33];
  const float* lin1_W   = (const float*)d_in[34];
  const float* lin1_b   = (const float*)d_in[35];
  const float* lin2_W   = (const float*)d_in[36];
  const float* lin2_b   = (const float*)d_in[37];
  const float* lin3_W   = (const float*)d_in[38];
  const float* lin3_b   = (const float*)d_in[39];
  float* out = (float*)d_out;

  // ---- workspace layout (floats then ints) ----
  float* wsf   = (float*)d_ws;
  float* R192  = wsf;                         // N x 192  (concat poi|svi)
  float* RA    = R192 + (size_t)N * 192;      // N x 128  (general)
  float* RA2   = RA + (size_t)N * 64;         // second N x 64 half of RA
  float* RB    = RA + (size_t)N * 128;        // N x 256  (gates / general)
  float* Rz    = RB + (size_t)N * 256;        // N x 128  (concat gat3|time)
  float* sArr  = Rz + (size_t)N * 128;        // N
  float* tArr  = sArr + N;                    // N
  int* ints      = (int*)(tArr + N);
  int* row_start = ints;                      // N+1  (also used as cnt)
  int* cursor    = row_start + (N + 1);       // N
  int* srcs      = cursor + N;                // Et
  int* blockSums = srcs + Et;                 // 256

  const int TB = 256;
  const int edgeBlocks = (Et + TB - 1) / TB;

  // ---- build CSR (dst-sorted src list); shared by all 3 GAT layers ----
  hipLaunchKernelGGL(fill_i32_kernel, dim3((N + TB - 1) / TB), dim3(TB), 0, stream,
                     row_start, 0, N);
  hipLaunchKernelGGL(count_edges_kernel, dim3(edgeBlocks), dim3(TB), 0, stream,
                     ei, row_start, E, N);
  hipLaunchKernelGGL(scan1_kernel, dim3(N / 256), dim3(256), 0, stream,
                     row_start, blockSums);
  hipLaunchKernelGGL(scan2_kernel, dim3(1), dim3(256), 0, stream, blockSums);
  hipLaunchKernelGGL(scan3_kernel, dim3(N / 256), dim3(256), 0, stream,
                     row_start, cursor, blockSums, N, Et);
  hipLaunchKernelGGL(scatter_kernel, dim3(edgeBlocks), dim3(TB), 0, stream,
                     ei, cursor, srcs, E, N);

  // ---- MLP towers ----
  // poi: x[:,3:16] -> 64 -> 64 (into R192 cols 0..63)
  launch_gemm(x + 3, 445, poi1_W, 64, poi1_b, RA, 64, N, 13, 64, 1, stream);
  launch_gemm(RA, 64, poi2_W, 64, poi2_b, R192, 192, N, 64, 64, 1, stream);
  // svi: x[:,56:421] -> 128 -> 128 (into R192 cols 64..191)
  launch_gemm(x + 56, 445, svi1_W, 128, svi1_b, RB, 128, N, 365, 128, 1, stream);
  launch_gemm(RB, 128, svi2_W, 128, svi2_b, R192 + 64, 192, N, 128, 128, 1, stream);
  // all: 192 -> 128 -> 128  => H in RB
  launch_gemm(R192, 192, all1_W, 128, all1_b, RA, 128, N, 192, 128, 1, stream);
  launch_gemm(RA, 128, all2_W, 128, all2_b, RB, 128, N, 128, 128, 1, stream);

  const int waveBlocks = N / 4;  // 4 waves (dst nodes) per 256-thread block

  // ---- GAT1: RB(H) -> RA(G) -> aggregate -> RB(H2) ----
  launch_gemm(RB, 128, gat1_W, 128, nullptr, RA, 128, N, 128, 128, 0, stream);
  hipLaunchKernelGGL(st_kernel, dim3(waveBlocks), dim3(256), 0, stream,
                     RA, gat1_as, gat1_ad, sArr, tArr, N, 128);
  hipLaunchKernelGGL((gat_aggregate<128>), dim3(waveBlocks), dim3(256), 0, stream,
                     RA, sArr, tArr, row_start, srcs, gat1_b, RB, 128, N);
  // ---- GAT2 ----
  launch_gemm(RB, 128, gat2_W, 128, nullptr, RA, 128, N, 128, 128, 0, stream);
  hipLaunchKernelGGL(st_kernel, dim3(waveBlocks), dim3(256), 0, stream,
                     RA, gat2_as, gat2_ad, sArr, tArr, N, 128);
  hipLaunchKernelGGL((gat_aggregate<128>), dim3(waveBlocks), dim3(256), 0, stream,
                     RA, sArr, tArr, row_start, srcs, gat2_b, RB, 128, N);
  // ---- GAT3 (fo=64, output into Rz cols 0..63) ----
  launch_gemm(RB, 128, gat3_W, 64, nullptr, RA, 64, N, 128, 64, 0, stream);
  hipLaunchKernelGGL(st_kernel, dim3(waveBlocks), dim3(256), 0, stream,
                     RA, gat3_as, gat3_ad, sArr, tArr, N, 64);
  hipLaunchKernelGGL((gat_aggregate<64>), dim3(waveBlocks), dim3(256), 0, stream,
                     RA, sArr, tArr, row_start, srcs, gat3_b, Rz, 128, N);

  // ---- "LSTM": only layers 0..2 matter (t = hs[2]); Whh/f-gate/cell unused ----
  const int actBlocks = (N * 64 + TB - 1) / TB;
  launch_gemm(x + 421, 445, lstm_Wih0, 256, lstm_b, RB, 256, N, 24, 256, 0, stream);
  hipLaunchKernelGGL(lstm_act_kernel, dim3(actBlocks), dim3(TB), 0, stream, RB, RA, N);
  launch_gemm(RA, 64, lstm_Wih, 256, lstm_b + 256, RB, 256, N, 64, 256, 0, stream);
  hipLaunchKernelGGL(lstm_act_kernel, dim3(actBlocks), dim3(TB), 0, stream, RB, RA2, N);
  launch_gemm(RA2, 64, lstm_Wih + 64 * 256, 256, lstm_b + 512, RB, 256, N, 64, 256, 0, stream);
  hipLaunchKernelGGL(lstm_act_kernel, dim3(actBlocks), dim3(TB), 0, stream, RB, RA, N);

  // ---- time MLP: h2 -> 64 -> 64 (into Rz cols 64..127) ----
  launch_gemm(RA, 64, time1_W, 64, time1_b, RA2, 64, N, 64, 64, 1, stream);
  launch_gemm(RA2, 64, time2_W, 64, time2_b, Rz + 64, 128, N, 64, 64, 1, stream);

  // ---- head: z = [gat3|time] (N x 128) -> 64 -> 64 -> 1 ----
  launch_gemm(Rz, 128, lin1_W, 64, lin1_b, RA, 64, N, 128, 64, 1, stream);
  launch_gemm(RA, 64, lin2_W, 64, lin2_b, RA2, 64, N, 64, 64, 1, stream);
  hipLaunchKernelGGL(lin3_kernel, dim3((N + TB - 1) / TB), dim3(TB), 0, stream,
                     RA2, lin3_W, lin3_b, out, N);
}